// Round 7
// baseline (786.722 us; speedup 1.0000x reference)
//
#include <hip/hip_runtime.h>
#include <hip/hip_fp16.h>

#define BB 256
#define TT 2048
#define FF 64
#define HH 32
#define G4 128
#define K2E 1.4426950408889634f

typedef float f32x2 __attribute__((ext_vector_type(2)));

__device__ __forceinline__ float fast_rcp(float x){ return __builtin_amdgcn_rcpf(x); }
__device__ __forceinline__ float fast_exp2(float x){
#if __has_builtin(__builtin_amdgcn_exp2f)
  return __builtin_amdgcn_exp2f(x);
#else
  return exp2f(x);
#endif
}
// v_permlane32_swap_b32: with a==b==v on input, outputs become the two
// half-broadcasts of v in a HW-fixed order; resolved at runtime by a probe.
__device__ __forceinline__ void swap_halves(float &a, float &b){
#if __has_builtin(__builtin_amdgcn_permlane32_swap)
  typedef int i32x2_ __attribute__((ext_vector_type(2)));
  i32x2_ r = __builtin_amdgcn_permlane32_swap(__float_as_int(a), __float_as_int(b), false, false);
  a = __int_as_float(r.x);
  b = __int_as_float(r.y);
#else
  asm("v_permlane32_swap_b32 %0, %1" : "+v"(a), "+v"(b));
#endif
}

#define PKFMA_VV(acc, a, b) asm("v_pk_fma_f32 %0, %1, %2, %0" : "+v"(acc) : "v"(a), "v"(b))
// D = S0.x*S1.x + S0.y*S1.y + S2  (f16 pairs, f32 accumulate); S0 from SGPR
#define DOT2_SV(acc, hs, wv) asm("v_dot2_f32_f16 %0, %1, %2, %0" : "+v"(acc) : "s"(hs), "v"(wv))

// ---------------- Phase 1: xg = (x @ Wx + b) * colscale, PAIRED layout ----------
// xg2[row][t] = 64 float2: element p<32 -> (i_p, f_p); p>=32 -> (g_{p-32}, o_{p-32}).
// colscale folds exp->exp2 + sigmoid/tanh arg scaling: i,f,o: -log2e ; g: +2*log2e.
__global__ __launch_bounds__(256) void lstm_gemm(const float* __restrict__ x,
    const float* __restrict__ Wx, const float* __restrict__ bias,
    float* __restrict__ xg, int t0, int ct)
{
  __shared__ float sW[FF*G4];
  __shared__ float sB[G4];
  __shared__ float sX[64*68];
  int tid = threadIdx.x;
  {
    const float4* Wx4 = (const float4*)Wx;
    float4* sW4 = (float4*)sW;
#pragma unroll
    for (int q=0;q<8;q++) sW4[q*256+tid] = Wx4[q*256+tid];
    if (tid < 32) ((float4*)sB)[tid] = ((const float4*)bias)[tid];
  }
  long total = (long)BB*ct;
  long m0 = (long)blockIdx.x * 64;
#pragma unroll
  for (int s=0;s<4;s++){
    int idx = tid + s*256;
    int row = idx >> 4, q = idx & 15;
    long gm = m0 + row;
    float4 v = make_float4(0.f,0.f,0.f,0.f);
    if (gm < total){
      int bidx = (int)((unsigned long)gm / (unsigned)ct);
      int tt   = (int)(gm - (long)bidx*ct);
      v = ((const float4*)(x + ((size_t)bidx*TT + t0 + tt)*FF))[q];
    }
    *(float4*)&sX[row*68 + q*4] = v;
  }
  __syncthreads();
  int rg = tid >> 5;
  int cg = tid & 31;
  int r0 = rg*8;
  f32x2 acc[8][4];
#pragma unroll
  for (int r=0;r<8;r++)
#pragma unroll
    for (int c=0;c<4;c++) acc[r][c] = (f32x2){0.f,0.f};
#pragma unroll 8
  for (int kp=0; kp<32; kp++){
    int k = kp*2;
    f32x2 xv[8];
#pragma unroll
    for (int r=0;r<8;r++) xv[r] = *(const f32x2*)&sX[(r0+r)*68 + k];
    f32x2 wv[4];
#pragma unroll
    for (int c=0;c<4;c++){
      f32x2 w; w.x = sW[k*G4 + cg + 32*c]; w.y = sW[(k+1)*G4 + cg + 32*c];
      wv[c] = w;
    }
#pragma unroll
    for (int r=0;r<8;r++)
#pragma unroll
      for (int c=0;c<4;c++) PKFMA_VV(acc[r][c], xv[r], wv[c]);
  }
#pragma unroll
  for (int r=0;r<8;r++){
    long gm = m0 + r0 + r;
    if (gm < total){
      f32x2* o = (f32x2*)(xg + (size_t)gm*G4);
      f32x2 p0, p1;
      p0.x = (acc[r][0].x + acc[r][0].y + sB[cg])      * (-K2E);      // i_cg
      p0.y = (acc[r][1].x + acc[r][1].y + sB[cg+32])   * (-K2E);      // f_cg
      p1.x = (acc[r][2].x + acc[r][2].y + sB[cg+64])   * (2.f*K2E);   // g_cg
      p1.y = (acc[r][3].x + acc[r][3].y + sB[cg+96])   * (-K2E);      // o_cg
      o[cg]      = p0;
      o[cg + 32] = p1;
    }
  }
}

// ---------------- Phase 2: sequential scan, 2 rows/wave, f16 dot2 matvec ----------
// Rows rA=2*blockIdx.x, rB=rA+1 share Wh fragments; their independent dependency
// chains interleave to fill latency gaps. h/c of BOTH rows are maintained valid
// in all 64 lanes (half-swap trick), so stores are full-wave unconditional.
__global__ __launch_bounds__(64)
__attribute__((amdgpu_waves_per_eu(1,1)))
void lstm_scan(const float* __restrict__ xg,
    const float* __restrict__ Wh, float* __restrict__ ys,
    float* __restrict__ state, int t0, int ct)
{
  int rA = blockIdx.x * 2;
  int rB = rA + 1;
  int l = threadIdx.x;
  int j = l & 31;
  int half = l >> 5;
  int base = j + half*64;

  float ws0 = half ? (2.f*K2E) : (-K2E);   // col base: i (sig) or g (tanh)
  float ws1 = -K2E;                        // col base+32: f or o (both sig)
  unsigned wh0[16], wh1[16];
#pragma unroll
  for (int kk=0;kk<16;kk++){
    __half2 a  = __floats2half2_rn(Wh[(2*kk)*G4 + base]*ws0,    Wh[(2*kk+1)*G4 + base]*ws0);
    __half2 b_ = __floats2half2_rn(Wh[(2*kk)*G4 + base+32]*ws1, Wh[(2*kk+1)*G4 + base+32]*ws1);
    wh0[kk] = *(unsigned*)&a;
    wh1[kk] = *(unsigned*)&b_;
  }
#pragma unroll
  for (int kk=0;kk<16;kk++){ asm volatile("" : "+v"(wh0[kk]), "+v"(wh1[kk])); }

  float A0 = half ? -2.f : 1.f;
  float B0 = half ?  1.f : 0.f;

  // direction probe for permlane32_swap (loop-invariant)
  float da = (float)half, db = (float)half;
  swap_halves(da, db);
  bool flip = (da != 0.0f);

  float ccA, hA, ccB, hB;
  if (t0 == 0){ ccA = hA = ccB = hB = 0.f; }
  else {
    ccA = state[rA*HH + j];  hA = state[BB*HH + rA*HH + j];
    ccB = state[rB*HH + j];  hB = state[BB*HH + rB*HH + j];
  }

  const f32x2* xqA = (const f32x2*)(xg + (size_t)rA*ct*G4) + l;  // lane's pair, stride 64/t
  const f32x2* xqB = (const f32x2*)(xg + (size_t)rB*ct*G4) + l;
  // lane stores its half's row: lanes 0-31 -> row A, 32-63 -> row B
  float* ypS = ys + ((size_t)(rA+half)*TT + t0)*HH + j;

  auto PACK = [&](float h)->int{
    float hn = __int_as_float(__builtin_amdgcn_update_dpp(
        0, __float_as_int(h), 0xB1 /*quad_perm [1,0,3,2]*/, 0xF, 0xF, true));
    __half2 pk2 = __floats2half2_rn(h, hn);
    return *(int*)&pk2;
  };

  auto STEP2 = [&](f32x2 xa, f32x2 xb, int t){
    int pkA = PACK(hA);
    int pkB = PACK(hB);
    int hpA[16], hpB[16];
#pragma unroll
    for (int kk=0;kk<16;kk++){
      hpA[kk] = __builtin_amdgcn_readlane(pkA, 2*kk);
      hpB[kk] = __builtin_amdgcn_readlane(pkB, 2*kk);
    }
    float cA0=xa.x, cA1=0.f, dA0=xa.y, dA1=0.f;
    float cB0=xb.x, cB1=0.f, dB0=xb.y, dB1=0.f;
#pragma unroll
    for (int kk=0;kk<8;kk++){
      DOT2_SV(cA0, hpA[kk],   wh0[kk]);
      DOT2_SV(dA0, hpA[kk],   wh1[kk]);
      DOT2_SV(cB0, hpB[kk],   wh0[kk]);
      DOT2_SV(dB0, hpB[kk],   wh1[kk]);
      DOT2_SV(cA1, hpA[kk+8], wh0[kk+8]);
      DOT2_SV(dA1, hpA[kk+8], wh1[kk+8]);
      DOT2_SV(cB1, hpB[kk+8], wh0[kk+8]);
      DOT2_SV(dB1, hpB[kk+8], wh1[kk+8]);
    }
    float g0A = cA0+cA1, g1A = dA0+dA1;
    float g0B = cB0+cB1, g1B = dB0+dB1;
    // activations, A/B interleaved (independent chains)
    float t1A = fast_rcp(1.f + fast_exp2(g1A));                // sig(f) | sig(o)
    float t1B = fast_rcp(1.f + fast_exp2(g1B));
    float t0A = fmaf(A0, fast_rcp(1.f + fast_exp2(g0A)), B0);  // sig(i) | tanh(g)
    float t0B = fmaf(A0, fast_rcp(1.f + fast_exp2(g0B)), B0);
    float siA = t0A, tgA = t0A; swap_halves(siA, tgA);
    float siB = t0B, tgB = t0B; swap_halves(siB, tgB);
    float igA = siA * tgA;                                     // order-invariant
    float igB = siB * tgB;
    float e0A = t1A, e1A = t1A; swap_halves(e0A, e1A);
    float e0B = t1B, e1B = t1B; swap_halves(e0B, e1B);
    float sfA = flip ? e1A : e0A, soA = flip ? e0A : e1A;
    float sfB = flip ? e1B : e0B, soB = flip ? e0B : e1B;
    ccA = fmaf(sfA, ccA, igA);
    ccB = fmaf(sfB, ccB, igB);
    float tcA = fmaf(-2.f, fast_rcp(1.f + fast_exp2((2.f*K2E)*ccA)), 1.f);
    float tcB = fmaf(-2.f, fast_rcp(1.f + fast_exp2((2.f*K2E)*ccB)), 1.f);
    hA = soA * tcA;                                            // valid in ALL lanes
    hB = soB * tcB;
    ypS[(size_t)t*HH] = half ? hB : hA;                        // full-wave store, 2 rows
  };

  // depth-4 double-buffered prefetch ring per row
  f32x2 aA[4], aB[4], bA[4], bB[4];
#pragma unroll
  for (int u=0;u<4;u++){
    int t_ = (u < ct) ? u : (ct-1);
    aA[u] = xqA[(size_t)t_*64];
    aB[u] = xqB[(size_t)t_*64];
  }
  int tb = 0;
  for (; tb + 8 <= ct; tb += 8){
#pragma unroll
    for (int u=0;u<4;u++){
      int t_ = tb + 4 + u;
      bA[u] = xqA[(size_t)t_*64];
      bB[u] = xqB[(size_t)t_*64];
    }
#pragma unroll
    for (int u=0;u<4;u++) STEP2(aA[u], aB[u], tb+u);
#pragma unroll
    for (int u=0;u<4;u++){
      int t_ = tb + 8 + u; if (t_ > ct-1) t_ = ct-1;
      aA[u] = xqA[(size_t)t_*64];
      aB[u] = xqB[(size_t)t_*64];
    }
#pragma unroll
    for (int u=0;u<4;u++) STEP2(bA[u], bB[u], tb+4+u);
  }
  for (int t=tb; t<ct; ++t) STEP2(xqA[(size_t)t*64], xqB[(size_t)t*64], t);

  // full-wave state stores: lanes 0-31 write row A, 32-63 write row B
  state[(rA+half)*HH + j]         = half ? ccB : ccA;
  state[BB*HH + (rA+half)*HH + j] = half ? hB  : hA;
}

extern "C" void kernel_launch(void* const* d_in, const int* in_sizes, int n_in,
                              void* d_out, int out_size, void* d_ws, size_t ws_size,
                              hipStream_t stream)
{
  const float* x  = (const float*)d_in[0];
  const float* Wx = (const float*)d_in[1];
  const float* Wh = (const float*)d_in[2];
  const float* b  = (const float*)d_in[3];
  float* ys = (float*)d_out;
  char* ws = (char*)d_ws;
  float* state = (float*)ws;                 // c: BB*HH, h: BB*HH
  float* xg = (float*)(ws + 65536);
  size_t per_step = (size_t)BB * G4 * sizeof(float);
  size_t avail = ws_size > 65536 ? ws_size - 65536 : 0;
  long ctl = (long)(avail / per_step);
  int CT = (ctl >= TT) ? TT : (int)ctl;
  if (CT < 1) CT = 1;
  for (int t0 = 0; t0 < TT; t0 += CT){
    int ct = (TT - t0 < CT) ? (TT - t0) : CT;
    int wgs = (int)(((long)BB*ct + 63)/64);
    lstm_gemm<<<dim3(wgs), dim3(256), 0, stream>>>(x, Wx, b, xg, t0, ct);
    lstm_scan<<<dim3(BB/2), dim3(64), 0, stream>>>(xg, Wh, ys, state, t0, ct);
  }
}

// Round 10
// 571.412 us; speedup vs baseline: 1.3768x; 1.3768x over previous
//
#include <hip/hip_runtime.h>
#include <hip/hip_fp16.h>

#define BB 256
#define TT 2048
#define FF 64
#define HH 32
#define G4 128
#define K2E 1.4426950408889634f

typedef float f32x2 __attribute__((ext_vector_type(2)));

__device__ __forceinline__ float fast_rcp(float x){ return __builtin_amdgcn_rcpf(x); }
__device__ __forceinline__ float fast_exp2(float x){
#if __has_builtin(__builtin_amdgcn_exp2f)
  return __builtin_amdgcn_exp2f(x);
#else
  return exp2f(x);
#endif
}
// v_permlane32_swap_b32: with a==b==v on input, outputs become the two
// half-broadcasts of v in a HW-fixed order; resolved at runtime by a probe.
__device__ __forceinline__ void swap_halves(float &a, float &b){
#if __has_builtin(__builtin_amdgcn_permlane32_swap)
  typedef int i32x2_ __attribute__((ext_vector_type(2)));
  i32x2_ r = __builtin_amdgcn_permlane32_swap(__float_as_int(a), __float_as_int(b), false, false);
  a = __int_as_float(r.x);
  b = __int_as_float(r.y);
#else
  asm("v_permlane32_swap_b32 %0, %1" : "+v"(a), "+v"(b));
#endif
}

#define PKFMA_VV(acc, a, b) asm("v_pk_fma_f32 %0, %1, %2, %0" : "+v"(acc) : "v"(a), "v"(b))
// D = S0.x*S1.x + S0.y*S1.y + S2  (f16 pairs, f32 accumulate); S0 from SGPR
#define DOT2_SV(acc, hs, wv) asm("v_dot2_f32_f16 %0, %1, %2, %0" : "+v"(acc) : "s"(hs), "v"(wv))

// ---------------- Phase 1: xg = (x @ Wx + b) * colscale, PAIRED layout ----------
// xg2[row][t] = 64 float2: element p<32 -> (i_p, f_p); p>=32 -> (g_{p-32}, o_{p-32}).
// colscale folds exp->exp2 + sigmoid/tanh arg scaling: i,f,o: -log2e ; g: +2*log2e.
// Weight tile stored TRANSPOSED in LDS (sWt[c][k], pad 66) so the inner-loop
// k-pair weight read is one contiguous ds_read_b64 per column group.
__global__ __launch_bounds__(256) void lstm_gemm(const float* __restrict__ x,
    const float* __restrict__ Wx, const float* __restrict__ bias,
    float* __restrict__ xg, int t0, int ct)
{
  __shared__ float sWt[G4*66];    // [c][k], 33792 B
  __shared__ float sB[G4];
  __shared__ float sX[64*68];     // [r][k], pad 68
  int tid = threadIdx.x;
  {
    const float4* Wx4 = (const float4*)Wx;
#pragma unroll
    for (int q=0;q<8;q++){
      int f4 = q*256 + tid;            // flat float4 idx into Wx[64][128]
      int k  = f4 >> 5;                // row (k)
      int c4 = f4 & 31;                // float4 col group
      float4 v = Wx4[f4];
      sWt[(4*c4+0)*66 + k] = v.x;
      sWt[(4*c4+1)*66 + k] = v.y;
      sWt[(4*c4+2)*66 + k] = v.z;
      sWt[(4*c4+3)*66 + k] = v.w;
    }
    if (tid < 32) ((float4*)sB)[tid] = ((const float4*)bias)[tid];
  }
  long total = (long)BB*ct;
  long m0 = (long)blockIdx.x * 64;
#pragma unroll
  for (int s=0;s<4;s++){
    int idx = tid + s*256;
    int row = idx >> 4, q = idx & 15;
    long gm = m0 + row;
    float4 v = make_float4(0.f,0.f,0.f,0.f);
    if (gm < total){
      int bidx = (int)((unsigned long)gm / (unsigned)ct);
      int tt   = (int)(gm - (long)bidx*ct);
      v = ((const float4*)(x + ((size_t)bidx*TT + t0 + tt)*FF))[q];
    }
    *(float4*)&sX[row*68 + q*4] = v;
  }
  __syncthreads();
  int rg = tid >> 5;
  int cg = tid & 31;
  int r0 = rg*8;
  f32x2 acc[8][4];
#pragma unroll
  for (int r=0;r<8;r++)
#pragma unroll
    for (int c=0;c<4;c++) acc[r][c] = (f32x2){0.f,0.f};
#pragma unroll 8
  for (int kp=0; kp<32; kp++){
    int k = kp*2;
    f32x2 xv[8];
#pragma unroll
    for (int r=0;r<8;r++) xv[r] = *(const f32x2*)&sX[(r0+r)*68 + k];
    f32x2 wv[4];
#pragma unroll
    for (int c=0;c<4;c++) wv[c] = *(const f32x2*)&sWt[(cg+32*c)*66 + k];
#pragma unroll
    for (int r=0;r<8;r++)
#pragma unroll
      for (int c=0;c<4;c++) PKFMA_VV(acc[r][c], xv[r], wv[c]);
  }
#pragma unroll
  for (int r=0;r<8;r++){
    long gm = m0 + r0 + r;
    if (gm < total){
      f32x2* o = (f32x2*)(xg + (size_t)gm*G4);
      f32x2 p0, p1;
      p0.x = (acc[r][0].x + acc[r][0].y + sB[cg])      * (-K2E);      // i_cg
      p0.y = (acc[r][1].x + acc[r][1].y + sB[cg+32])   * (-K2E);      // f_cg
      p1.x = (acc[r][2].x + acc[r][2].y + sB[cg+64])   * (2.f*K2E);   // g_cg
      p1.y = (acc[r][3].x + acc[r][3].y + sB[cg+96])   * (-K2E);      // o_cg
      o[cg]      = p0;
      o[cg + 32] = p1;
    }
  }
}

// ---------------- Phase 2: sequential scan, 1 row/wave, f16 dot2 matvec ----------
// r6-verbatim structure: guarded (exec-masked) y/state stores. Empirical rule
// from r8/r9: duplicate-address multi-lane stores corrupt results even with
// provably identical values — keep the half==0 guard.
__global__ __launch_bounds__(64)
__attribute__((amdgpu_waves_per_eu(1,1)))
void lstm_scan(const float* __restrict__ xg,
    const float* __restrict__ Wh, float* __restrict__ ys,
    float* __restrict__ state, int t0, int ct)
{
  int r = blockIdx.x;
  int l = threadIdx.x;
  int j = l & 31;
  int half = l >> 5;
  int base = j + half*64;

  float ws0 = half ? (2.f*K2E) : (-K2E);   // col base: i (sig) or g (tanh)
  float ws1 = -K2E;                        // col base+32: f or o (both sig)
  unsigned wh0[16], wh1[16];
#pragma unroll
  for (int kk=0;kk<16;kk++){
    __half2 a  = __floats2half2_rn(Wh[(2*kk)*G4 + base]*ws0,    Wh[(2*kk+1)*G4 + base]*ws0);
    __half2 b_ = __floats2half2_rn(Wh[(2*kk)*G4 + base+32]*ws1, Wh[(2*kk+1)*G4 + base+32]*ws1);
    wh0[kk] = *(unsigned*)&a;
    wh1[kk] = *(unsigned*)&b_;
  }
#pragma unroll
  for (int kk=0;kk<16;kk++){ asm volatile("" : "+v"(wh0[kk]), "+v"(wh1[kk])); }

  float A0 = half ? -2.f : 1.f;
  float B0 = half ?  1.f : 0.f;

  // direction probe for permlane32_swap (loop-invariant)
  float da = (float)half, db = (float)half;
  swap_halves(da, db);
  bool flip = (da != 0.0f);

  float cc, hcur;
  if (t0 == 0){ cc = 0.f; hcur = 0.f; }
  else { cc = state[r*HH + j]; hcur = state[BB*HH + r*HH + j]; }

  const f32x2* xq = (const f32x2*)(xg + (size_t)r*ct*G4) + l;   // lane's pair, stride 64 per t
  float* yp = ys + ((size_t)r*TT + t0)*HH;

  auto STEP = [&](f32x2 xv, int t){
    // pack h into f16 pairs: even lane 2m holds (h[2m], h[2m+1])
    float hn = __int_as_float(__builtin_amdgcn_update_dpp(
        0, __float_as_int(hcur), 0xB1 /*quad_perm [1,0,3,2]*/, 0xF, 0xF, true));
    __half2 pk2 = __floats2half2_rn(hcur, hn);
    int pk = *(int*)&pk2;
    int hp[16];
#pragma unroll
    for (int kk=0;kk<16;kk++) hp[kk] = __builtin_amdgcn_readlane(pk, 2*kk);
    float c0=xv.x, c1=0.f, d0=xv.y, d1=0.f;
#pragma unroll
    for (int kk=0;kk<8;kk++){
      DOT2_SV(c0, hp[kk],   wh0[kk]);
      DOT2_SV(d0, hp[kk],   wh1[kk]);
      DOT2_SV(c1, hp[kk+8], wh0[kk+8]);
      DOT2_SV(d1, hp[kk+8], wh1[kk+8]);
    }
    float g0 = c0 + c1;
    float g1 = d0 + d1;
    float t1v = fast_rcp(1.f + fast_exp2(g1));                // lower: sig(f), upper: sig(o)
    float t0v = fmaf(A0, fast_rcp(1.f + fast_exp2(g0)), B0);  // lower: sig(i), upper: tanh(g)
    float si = t0v, tg = t0v;
    swap_halves(si, tg);
    float ig = si * tg;                                       // order-invariant product
    float e0 = t1v, e1 = t1v;
    swap_halves(e0, e1);
    float sf = flip ? e1 : e0;
    float so = flip ? e0 : e1;
    cc = fmaf(sf, cc, ig);
    float tc = fmaf(-2.f, fast_rcp(1.f + fast_exp2((2.f*K2E)*cc)), 1.f);
    hcur = so * tc;                                           // valid in ALL lanes
    if (half == 0) yp[(size_t)t*HH + j] = hcur;
  };

  f32x2 bufA[8], bufB[8];
#pragma unroll
  for (int u=0;u<8;u++){ int t_ = (u < ct) ? u : (ct-1); bufA[u] = xq[(size_t)t_*64]; }

  int tb = 0;
  for (; tb + 16 <= ct; tb += 16){
#pragma unroll
    for (int u=0;u<8;u++) bufB[u] = xq[(size_t)(tb+8+u)*64];
#pragma unroll
    for (int u=0;u<8;u++) STEP(bufA[u], tb+u);
#pragma unroll
    for (int u=0;u<8;u++){ int t_ = tb+16+u; if (t_ > ct-1) t_ = ct-1; bufA[u] = xq[(size_t)t_*64]; }
#pragma unroll
    for (int u=0;u<8;u++) STEP(bufB[u], tb+8+u);
  }
  for (int t=tb; t<ct; ++t) STEP(xq[(size_t)t*64], t);

  if (half == 0){
    state[r*HH + j] = cc;
    state[BB*HH + r*HH + j] = hcur;
  }
}

extern "C" void kernel_launch(void* const* d_in, const int* in_sizes, int n_in,
                              void* d_out, int out_size, void* d_ws, size_t ws_size,
                              hipStream_t stream)
{
  const float* x  = (const float*)d_in[0];
  const float* Wx = (const float*)d_in[1];
  const float* Wh = (const float*)d_in[2];
  const float* b  = (const float*)d_in[3];
  float* ys = (float*)d_out;
  char* ws = (char*)d_ws;
  float* state = (float*)ws;                 // c: BB*HH, h: BB*HH
  float* xg = (float*)(ws + 65536);
  size_t per_step = (size_t)BB * G4 * sizeof(float);
  size_t avail = ws_size > 65536 ? ws_size - 65536 : 0;
  long ctl = (long)(avail / per_step);
  int CT = (ctl >= TT) ? TT : (int)ctl;
  if (CT < 1) CT = 1;
  for (int t0 = 0; t0 < TT; t0 += CT){
    int ct = (TT - t0 < CT) ? (TT - t0) : CT;
    int wgs = (int)(((long)BB*ct + 63)/64);
    lstm_gemm<<<dim3(wgs), dim3(256), 0, stream>>>(x, Wx, b, xg, t0, ct);
    lstm_scan<<<dim3(BB), dim3(64), 0, stream>>>(xg, Wh, ys, state, t0, ct);
  }
}

// Round 14
// 525.744 us; speedup vs baseline: 1.4964x; 1.0869x over previous
//
#include <hip/hip_runtime.h>
#include <hip/hip_fp16.h>

#define BB 256
#define TT 2048
#define FF 64
#define HH 32
#define G4 128
#define K2E 1.4426950408889634f

typedef float f32x2 __attribute__((ext_vector_type(2)));

__device__ __forceinline__ float fast_rcp(float x){ return __builtin_amdgcn_rcpf(x); }
__device__ __forceinline__ float fast_exp2(float x){
#if __has_builtin(__builtin_amdgcn_exp2f)
  return __builtin_amdgcn_exp2f(x);
#else
  return exp2f(x);
#endif
}
// v_permlane32_swap_b32: with a==b==v on input, outputs become the two
// half-broadcasts of v in a HW-fixed order; resolved at runtime by a probe.
__device__ __forceinline__ void swap_halves(float &a, float &b){
#if __has_builtin(__builtin_amdgcn_permlane32_swap)
  typedef int i32x2_ __attribute__((ext_vector_type(2)));
  i32x2_ r = __builtin_amdgcn_permlane32_swap(__float_as_int(a), __float_as_int(b), false, false);
  a = __int_as_float(r.x);
  b = __int_as_float(r.y);
#else
  asm("v_permlane32_swap_b32 %0, %1" : "+v"(a), "+v"(b));
#endif
}

#define PKFMA_VV(acc, a, b) asm("v_pk_fma_f32 %0, %1, %2, %0" : "+v"(acc) : "v"(a), "v"(b))
// D = S0.x*S1.x + S0.y*S1.y + S2  (f16 pairs, f32 accumulate); S0 from SGPR
#define DOT2_SV(acc, hs, wv) asm("v_dot2_f32_f16 %0, %1, %2, %0" : "+v"(acc) : "s"(hs), "v"(wv))

// ---------------- Phase 1: xg = (x @ Wx + b) * colscale, PAIRED f32 layout -------
// xg2[row][t] = 64 float2: pair p<32 -> (i_p, f_p); p>=32 -> (g_{p-32}, o_{p-32}).
// colscale folds exp->exp2 + sigmoid/tanh arg scaling: i,f,o: -log2e ; g: +2*log2e.
// xg MUST remain f32: f16 xg (r13) compounds through the 2048-step c-recurrence
// for forget-saturated units (gain ~1/(1-f)) -> absmax 0.096 >> 0.0187 budget.
__global__ __launch_bounds__(256) void lstm_gemm(const float* __restrict__ x,
    const float* __restrict__ Wx, const float* __restrict__ bias,
    float* __restrict__ xg, int t0, int ct)
{
  __shared__ float sW[FF*G4];
  __shared__ float sB[G4];
  __shared__ float sX[64*68];
  int tid = threadIdx.x;
  {
    const float4* Wx4 = (const float4*)Wx;
    float4* sW4 = (float4*)sW;
#pragma unroll
    for (int q=0;q<8;q++) sW4[q*256+tid] = Wx4[q*256+tid];
    if (tid < 32) ((float4*)sB)[tid] = ((const float4*)bias)[tid];
  }
  long total = (long)BB*ct;
  long m0 = (long)blockIdx.x * 64;
#pragma unroll
  for (int s=0;s<4;s++){
    int idx = tid + s*256;
    int row = idx >> 4, q = idx & 15;
    long gm = m0 + row;
    float4 v = make_float4(0.f,0.f,0.f,0.f);
    if (gm < total){
      int bidx = (int)((unsigned long)gm / (unsigned)ct);
      int tt   = (int)(gm - (long)bidx*ct);
      v = ((const float4*)(x + ((size_t)bidx*TT + t0 + tt)*FF))[q];
    }
    *(float4*)&sX[row*68 + q*4] = v;
  }
  __syncthreads();
  int rg = tid >> 5;
  int cg = tid & 31;
  int r0 = rg*8;
  f32x2 acc[8][4];
#pragma unroll
  for (int r=0;r<8;r++)
#pragma unroll
    for (int c=0;c<4;c++) acc[r][c] = (f32x2){0.f,0.f};
#pragma unroll 8
  for (int kp=0; kp<32; kp++){
    int k = kp*2;
    f32x2 xv[8];
#pragma unroll
    for (int r=0;r<8;r++) xv[r] = *(const f32x2*)&sX[(r0+r)*68 + k];
    f32x2 wv[4];
#pragma unroll
    for (int c=0;c<4;c++){
      f32x2 w; w.x = sW[k*G4 + cg + 32*c]; w.y = sW[(k+1)*G4 + cg + 32*c];
      wv[c] = w;
    }
#pragma unroll
    for (int r=0;r<8;r++)
#pragma unroll
      for (int c=0;c<4;c++) PKFMA_VV(acc[r][c], xv[r], wv[c]);
  }
#pragma unroll
  for (int r=0;r<8;r++){
    long gm = m0 + r0 + r;
    if (gm < total){
      f32x2* o = (f32x2*)(xg + (size_t)gm*G4);
      f32x2 p0, p1;
      p0.x = (acc[r][0].x + acc[r][0].y + sB[cg])      * (-K2E);      // i_cg
      p0.y = (acc[r][1].x + acc[r][1].y + sB[cg+32])   * (-K2E);      // f_cg
      p1.x = (acc[r][2].x + acc[r][2].y + sB[cg+64])   * (2.f*K2E);   // g_cg
      p1.y = (acc[r][3].x + acc[r][3].y + sB[cg+96])   * (-K2E);      // o_cg
      o[cg]      = p0;
      o[cg + 32] = p1;
    }
  }
}

// ---------------- Phase 2: sequential scan, 1 row/wave, f16 dot2 matvec ----------
// r6-verbatim (PROVEN passing at 418 us): guarded exec-masked y/state stores
// (rule from r8/r9: never store the same address from two lanes), SGPR readlane
// h-broadcast, permlane-swap gate exchange with runtime direction probe.
__global__ __launch_bounds__(64)
__attribute__((amdgpu_waves_per_eu(1,1)))
void lstm_scan(const float* __restrict__ xg,
    const float* __restrict__ Wh, float* __restrict__ ys,
    float* __restrict__ state, int t0, int ct)
{
  int r = blockIdx.x;
  int l = threadIdx.x;
  int j = l & 31;
  int half = l >> 5;
  int base = j + half*64;

  float ws0 = half ? (2.f*K2E) : (-K2E);   // col base: i (sig) or g (tanh)
  float ws1 = -K2E;                        // col base+32: f or o (both sig)
  unsigned wh0[16], wh1[16];
#pragma unroll
  for (int kk=0;kk<16;kk++){
    __half2 a  = __floats2half2_rn(Wh[(2*kk)*G4 + base]*ws0,    Wh[(2*kk+1)*G4 + base]*ws0);
    __half2 b_ = __floats2half2_rn(Wh[(2*kk)*G4 + base+32]*ws1, Wh[(2*kk+1)*G4 + base+32]*ws1);
    wh0[kk] = *(unsigned*)&a;
    wh1[kk] = *(unsigned*)&b_;
  }
#pragma unroll
  for (int kk=0;kk<16;kk++){ asm volatile("" : "+v"(wh0[kk]), "+v"(wh1[kk])); }

  float A0 = half ? -2.f : 1.f;
  float B0 = half ?  1.f : 0.f;

  // direction probe for permlane32_swap (loop-invariant)
  float da = (float)half, db = (float)half;
  swap_halves(da, db);
  bool flip = (da != 0.0f);

  float cc, hcur;
  if (t0 == 0){ cc = 0.f; hcur = 0.f; }
  else { cc = state[r*HH + j]; hcur = state[BB*HH + r*HH + j]; }

  const f32x2* xq = (const f32x2*)(xg + (size_t)r*ct*G4) + l;   // lane's pair, stride 64 per t
  float* yp = ys + ((size_t)r*TT + t0)*HH;

  auto STEP = [&](f32x2 xv, int t){
    // pack h into f16 pairs: even lane 2m holds (h[2m], h[2m+1])
    float hn = __int_as_float(__builtin_amdgcn_update_dpp(
        0, __float_as_int(hcur), 0xB1 /*quad_perm [1,0,3,2]*/, 0xF, 0xF, true));
    __half2 pk2 = __floats2half2_rn(hcur, hn);
    int pk = *(int*)&pk2;
    int hp[16];
#pragma unroll
    for (int kk=0;kk<16;kk++) hp[kk] = __builtin_amdgcn_readlane(pk, 2*kk);
    float c0=xv.x, c1=0.f, d0=xv.y, d1=0.f;
#pragma unroll
    for (int kk=0;kk<8;kk++){
      DOT2_SV(c0, hp[kk],   wh0[kk]);
      DOT2_SV(d0, hp[kk],   wh1[kk]);
      DOT2_SV(c1, hp[kk+8], wh0[kk+8]);
      DOT2_SV(d1, hp[kk+8], wh1[kk+8]);
    }
    float g0 = c0 + c1;
    float g1 = d0 + d1;
    float t1v = fast_rcp(1.f + fast_exp2(g1));                // lower: sig(f), upper: sig(o)
    float t0v = fmaf(A0, fast_rcp(1.f + fast_exp2(g0)), B0);  // lower: sig(i), upper: tanh(g)
    float si = t0v, tg = t0v;
    swap_halves(si, tg);
    float ig = si * tg;                                       // order-invariant product
    float e0 = t1v, e1 = t1v;
    swap_halves(e0, e1);
    float sf = flip ? e1 : e0;
    float so = flip ? e0 : e1;
    cc = fmaf(sf, cc, ig);
    float tc = fmaf(-2.f, fast_rcp(1.f + fast_exp2((2.f*K2E)*cc)), 1.f);
    hcur = so * tc;                                           // valid in ALL lanes
    if (half == 0) yp[(size_t)t*HH + j] = hcur;
  };

  f32x2 bufA[8], bufB[8];
#pragma unroll
  for (int u=0;u<8;u++){ int t_ = (u < ct) ? u : (ct-1); bufA[u] = xq[(size_t)t_*64]; }

  int tb = 0;
  for (; tb + 16 <= ct; tb += 16){
#pragma unroll
    for (int u=0;u<8;u++) bufB[u] = xq[(size_t)(tb+8+u)*64];
#pragma unroll
    for (int u=0;u<8;u++) STEP(bufA[u], tb+u);
#pragma unroll
    for (int u=0;u<8;u++){ int t_ = tb+16+u; if (t_ > ct-1) t_ = ct-1; bufA[u] = xq[(size_t)t_*64]; }
#pragma unroll
    for (int u=0;u<8;u++) STEP(bufB[u], tb+8+u);
  }
  for (int t=tb; t<ct; ++t) STEP(xq[(size_t)t*64], t);

  if (half == 0){
    state[r*HH + j] = cc;
    state[BB*HH + r*HH + j] = hcur;
  }
}

extern "C" void kernel_launch(void* const* d_in, const int* in_sizes, int n_in,
                              void* d_out, int out_size, void* d_ws, size_t ws_size,
                              hipStream_t stream)
{
  const float* x  = (const float*)d_in[0];
  const float* Wx = (const float*)d_in[1];
  const float* Wh = (const float*)d_in[2];
  const float* b  = (const float*)d_in[3];
  float* ys = (float*)d_out;
  char* ws = (char*)d_ws;
  float* state = (float*)ws;                 // c: BB*HH, h: BB*HH
  float* xg = (float*)(ws + 65536);
  size_t per_step = (size_t)BB * G4 * sizeof(float);
  size_t avail = ws_size > 65536 ? ws_size - 65536 : 0;
  long ctl = (long)(avail / per_step);
  int CT = (ctl >= TT) ? TT : (int)ctl;
  if (CT < 1) CT = 1;
  for (int t0 = 0; t0 < TT; t0 += CT){
    int ct = (TT - t0 < CT) ? (TT - t0) : CT;
    int wgs = (int)(((long)BB*ct + 63)/64);
    lstm_gemm<<<dim3(wgs), dim3(256), 0, stream>>>(x, Wx, b, xg, t0, ct);
    lstm_scan<<<dim3(BB), dim3(64), 0, stream>>>(xg, Wh, ys, state, t0, ct);
  }
}